// Round 6
// baseline (571.256 us; speedup 1.0000x reference)
//
#include <hip/hip_runtime.h>

// ============================================================================
// CharLevelEncoder R6: weight-stationary persistent LSTM, K=64 i8 MFMA,
// 1024-thr blocks (16 waves/CU, 4/SIMD for cross-wave pipe overlap).
// Wave w owns 64 gate cols (gates g=0..3 of hidden units [w*16,w*16+16)):
// full W' = 80 VGPRs/wave. Cell state c in LDS (b32 conflict-free).
// R5 evidence: pipes were serialized (Mfma 24.6% + VALU 38%); trans floor
// (2560 quarter-rate insts/step/CU) is the predicted new binding pipe.
// ============================================================================

#define NW 32768

typedef __attribute__((ext_vector_type(8))) short short8;
typedef __attribute__((ext_vector_type(4))) float f32x4;
typedef __attribute__((ext_vector_type(4))) int i32x4;

#define MFMA16(a,b,c)  __builtin_amdgcn_mfma_f32_16x16x32_bf16(a,b,c,0,0,0)
#define MFMAI64(a,b,c) __builtin_amdgcn_mfma_i32_16x16x64_i8(a,b,c,0,0,0)

// ---- workspace layout (bytes) ----
#define O_ORDER 0                      // i32[32768] sorted word ids (asc len)
#define O_SLEN  131072                 // i32[32768] sorted lengths
#define O_WPK   262144                 // i8 packed W' K64-fragments (327680)
#define O_USTP  589824                 // f32[1024] rowmax/(127*127)
#define O_BIAS  593920                 // f32[1024] b_ih + b_hh
#define O_CHT   598016                 // i8[256][64] chartab = rint(508*E)
#define O_WLIN  614400                 // bf16 packed W_lin fragments (262144)
#define O_HP    876544                 // u32[16][16] hist partials
#define O_POS   877568                 // i32[16] bucket cursors

__device__ inline unsigned short f2b(float f) {   // fp32 -> bf16 RNE
  unsigned u = __builtin_bit_cast(unsigned, f);
  u = u + 0x7fffu + ((u >> 16) & 1u);
  return (unsigned short)(u >> 16);
}
__device__ inline float fsigm(float x) {
  float e = __builtin_amdgcn_exp2f(-1.44269504f * x);
  return __builtin_amdgcn_rcpf(1.0f + e);
}
__device__ inline float ftanh(float x) {
  float e = __builtin_amdgcn_exp2f(2.88539008f * x);
  return 1.0f - 2.0f * __builtin_amdgcn_rcpf(e + 1.0f);
}

// ---- prepA: row scales (wave-per-row), bias, chartab, hist partials ----
__global__ void k_prepA(const float* __restrict__ wih, const float* __restrict__ whh,
                        const float* __restrict__ bih, const float* __restrict__ bhh,
                        const float* __restrict__ ech, const int* __restrict__ lens,
                        unsigned char* __restrict__ ws) {
  int b = blockIdx.x, tid = threadIdx.x;
  if (b < 256) {                        // 4 waves/block, wave-per-row rowmax
    int n = b * 4 + (tid >> 6), lane = tid & 63;
    float m = fabsf(wih[n * 64 + lane]) * 0.25f;
    #pragma unroll
    for (int c = 0; c < 4; ++c) m = fmaxf(m, fabsf(whh[n * 256 + c * 64 + lane]));
    #pragma unroll
    for (int off = 32; off; off >>= 1) m = fmaxf(m, __shfl_xor(m, off));
    if (lane == 0) {
      ((float*)(ws + O_USTP))[n] = m / 16129.f;    // rowmax/(127*127)
      ((float*)(ws + O_BIAS))[n] = bih[n] + bhh[n];
    }
    return;
  }
  if (b < 320) {                        // chartab: rint(508*E) clamp ±127
    int idx = (b - 256) * 256 + tid;
    int q = (int)__builtin_rintf(508.f * ech[idx]);
    q = q < -127 ? -127 : (q > 127 ? 127 : q);
    ((signed char*)(ws + O_CHT))[idx] = (signed char)q;
    return;
  }
  // hist partials: 16 blocks x 2048 words
  __shared__ unsigned hist[16];
  int blk = b - 320;
  if (tid < 16) hist[tid] = 0;
  __syncthreads();
  #pragma unroll
  for (int i = 0; i < 8; ++i) {
    int w = blk * 2048 + i * 256 + tid;
    int l = lens[w]; l = l < 1 ? 1 : (l > 16 ? 16 : l);
    atomicAdd(&hist[l - 1], 1u);
  }
  __syncthreads();
  if (tid < 16) ((unsigned*)(ws + O_HP))[blk * 16 + tid] = hist[tid];
}

// ---- prepB: pack W' i8 K64-fragments + W_lin bf16 fragments + scan ----
// WPK flat byte: (((w*5+kb)*4+g)*64+lane)*16 + j
//   n = g*256 + w*16 + (lane&15);  k = kb*64 + (lane>>4)*16 + j
__global__ void k_prepB(const float* __restrict__ wih, const float* __restrict__ whh,
                        const float* __restrict__ wlin, unsigned char* __restrict__ ws) {
  int b = blockIdx.x, tid = threadIdx.x;
  int i = b * 256 + tid;
  if (b < 1280) {                       // 327680 W' bytes
    int j = i & 15, lane = (i >> 4) & 63, t = i >> 10;
    int g = t & 3, u = t >> 2;
    int kb = u % 5, w = u / 5;
    int n = g * 256 + w * 16 + (lane & 15);
    int k = kb * 64 + (lane >> 4) * 16 + j;
    float v = (k < 64) ? wih[n * 64 + k] * 0.25f : whh[n * 256 + (k - 64)];
    float ustep = ((const float*)(ws + O_USTP))[n] * 127.f;
    float qf = (ustep > 0.f) ? v / ustep : 0.f;
    int q = (int)__builtin_rintf(qf);
    q = q < -127 ? -127 : (q > 127 ? 127 : q);
    ((signed char*)(ws + O_WPK))[i] = (signed char)q;
    return;
  }
  if (b < 1792) {                       // W_lin pack (layout verified R4/R5)
    int i2 = i - 327680;
    int j = i2 & 7, lane = (i2 >> 3) & 63, t3 = i2 >> 9;
    int kf = t3 & 15, nn = t3 >> 4;
    int n = (nn >> 2) * 64 + (nn & 3) * 16 + (lane & 15);
    int k = kf * 32 + (lane >> 4) * 8 + j;
    ((unsigned short*)(ws + O_WLIN))[i2] = f2b(wlin[n * 512 + k]);
    return;
  }
  if (tid == 0) {                       // scan hist partials -> bucket starts
    const unsigned* hp = (const unsigned*)(ws + O_HP);
    int* pos = (int*)(ws + O_POS);
    unsigned acc = 0;
    for (int l = 0; l < 16; ++l) {
      unsigned s = 0;
      for (int blk = 0; blk < 16; ++blk) s += hp[blk * 16 + l];
      pos[l] = (int)acc; acc += s;
    }
  }
}

// ---- scatter: parallel counting-sort placement ----
__global__ void k_scatter(const int* __restrict__ lens, unsigned char* __restrict__ ws) {
  int w = blockIdx.x * 256 + threadIdx.x;
  int l = lens[w]; l = l < 1 ? 1 : (l > 16 ? 16 : l);
  int p = atomicAdd((int*)(ws + O_POS) + (l - 1), 1);
  ((int*)(ws + O_ORDER))[p] = w;
  ((int*)(ws + O_SLEN))[p]  = l;
}

// ---- main: 256 blocks x 1024 threads (16 waves), 64 words/block ----
// LDS: CRG f32[16][1024] 64K | Xb i8[4][5][64][16] 20K | CT 16K | CW 4K
#define L_XB  65536
#define L_CT  86016
#define L_CW  102400

__global__ __launch_bounds__(1024, 4) void k_main(
    const int* __restrict__ cidx, const float* __restrict__ wemb,
    const float* __restrict__ blin, float* __restrict__ outp,
    const unsigned char* __restrict__ ws) {
  extern __shared__ unsigned char smem[];
  float* CRG = (float*)smem;                       // [mt*4+r][1024]
  signed char (*Xb)[5][64][16] = (signed char (*)[5][64][16])(smem + L_XB);
  signed char (*CT)[64] = (signed char (*)[64])(smem + L_CT);
  int (*CW)[16] = (int (*)[16])(smem + L_CW);

  const int tid = threadIdx.x, b = blockIdx.x;
  const int w = tid >> 6, lane = tid & 63;
  const int q = lane >> 4, l15 = lane & 15;

  const int* order = (const int*)(ws + O_ORDER);
  const int* slen  = (const int*)(ws + O_SLEN);
  const signed char* wpk = (const signed char*)(ws + O_WPK);
  const unsigned short* wlin = (const unsigned short*)(ws + O_WLIN);

  // prologue: chartab -> LDS, W' -> VGPR (80), dequant consts
  ((i32x4*)CT)[tid] = ((const i32x4*)(ws + O_CHT))[tid];
  i32x4 wreg[5][4];
  #pragma unroll
  for (int kb = 0; kb < 5; ++kb)
    #pragma unroll
    for (int g = 0; g < 4; ++g)
      wreg[kb][g] = *(const i32x4*)(wpk + (((w * 5 + kb) * 4 + g) * 64 + lane) * 16);
  float uq[4], bq[4];
  #pragma unroll
  for (int g = 0; g < 4; ++g) {
    int n = g * 256 + w * 16 + l15;
    uq[g] = ((const float*)(ws + O_USTP))[n];
    bq[g] = ((const float*)(ws + O_BIAS))[n];
  }
  const int mt0 = w >> 2, nw = w & 3;              // epilogue roles
  float blv[4];
  #pragma unroll
  for (int nt = 0; nt < 4; ++nt) blv[nt] = blin[nw * 64 + nt * 16 + l15];

  // two balanced slices {b, 511-b}
  for (int sl = 0; sl < 2; ++sl) {
    const int s = sl ? (511 - b) : b;
    const int base = 64 * s;
    __syncthreads();                   // prologue / previous epilogue done

    // zero Xb (1280 x 16B) and CRG (4096 x 16B)
    ((i32x4*)Xb)[tid] = (i32x4)0;
    if (tid < 256) ((i32x4*)Xb)[1024 + tid] = (i32x4)0;
    #pragma unroll
    for (int i = 0; i < 4; ++i) ((i32x4*)CRG)[tid + 1024 * i] = (i32x4)0;
    if (tid < 256) {                   // char indices for this slice
      int m = tid >> 2, part = tid & 3;
      int wid = order[base + m];
      *(i32x4*)&CW[m][part * 4] = *(const i32x4*)(cidx + wid * 16 + part * 4);
    }
    int tmax[4]; unsigned lenpk[4];
    #pragma unroll
    for (int mt = 0; mt < 4; ++mt) {
      int pbm = base + 16 * mt;
      tmax[mt] = slen[pbm + 15];
      unsigned l0 = (unsigned)slen[pbm + q * 4 + 0];
      unsigned l1 = (unsigned)slen[pbm + q * 4 + 1];
      unsigned l2 = (unsigned)slen[pbm + q * 4 + 2];
      unsigned l3 = (unsigned)slen[pbm + q * 4 + 3];
      lenpk[mt] = l0 | (l1 << 8) | (l2 << 16) | (l3 << 24);
    }
    const int Tm = tmax[3];
    __syncthreads();
    if (tid < 256) {                   // stage x' for t=0
      int m = tid >> 2, c = tid & 3;
      int ch = CW[m][0] & 255;
      *(i32x4*)&Xb[m >> 4][0][(m & 15) + 16 * c][0] = *(const i32x4*)&CT[ch][c * 16];
    }
    __syncthreads();

    unsigned hpack[4];

    for (int t = 0; t < Tm; ++t) {
      bool actm[4];
      actm[0] = t < tmax[0]; actm[1] = t < tmax[1];
      actm[2] = t < tmax[2]; actm[3] = true;

      #pragma unroll
      for (int mt = 0; mt < 4; ++mt) {
        if (!actm[mt]) continue;       // wave-uniform
        i32x4 acc[4];
        #pragma unroll
        for (int g = 0; g < 4; ++g) acc[g] = (i32x4)0;
        #pragma unroll
        for (int kb = 0; kb < 5; ++kb) {
          i32x4 A = *(const i32x4*)&Xb[mt][kb][lane][0];
          #pragma unroll
          for (int g = 0; g < 4; ++g) acc[g] = MFMAI64(A, wreg[kb][g], acc[g]);
        }
        // LSTM update: lane owns unit w*16+l15, words q*4+r of tile mt
        unsigned hp = 0;
        #pragma unroll
        for (int r = 0; r < 4; ++r) {
          float gi = (float)acc[0][r] * uq[0] + bq[0];
          float gf = (float)acc[1][r] * uq[1] + bq[1];
          float gg = (float)acc[2][r] * uq[2] + bq[2];
          float go = (float)acc[3][r] * uq[3] + bq[3];
          float si = fsigm(gi), sf = fsigm(gf);
          float sg = ftanh(gg), so = fsigm(go);
          float cold = CRG[(mt * 4 + r) * 1024 + tid];
          float cn = sf * cold + si * sg;
          float hn = so * ftanh(cn);
          int lene = (int)((lenpk[mt] >> (8 * r)) & 255u);
          CRG[(mt * 4 + r) * 1024 + tid] = (t < lene) ? cn : cold;
          int hq = (int)__builtin_rintf(127.f * hn);
          hq = hq < -127 ? -127 : (hq > 127 ? 127 : hq);
          hp |= ((unsigned)hq & 255u) << (8 * r);
        }
        hpack[mt] = hp;
      }
      __syncthreads();                 // all Xb reads of step t done

      // h write-back: unit u=w*16+l15 -> Xb[mt][1+(w>>2)][(q*4+r)+16*(w&3)][l15]
      #pragma unroll
      for (int mt = 0; mt < 4; ++mt) {
        if (!actm[mt]) continue;
        #pragma unroll
        for (int r = 0; r < 4; ++r) {
          int lene = (int)((lenpk[mt] >> (8 * r)) & 255u);
          if (t < lene)
            Xb[mt][1 + (w >> 2)][(q * 4 + r) + 16 * (w & 3)][l15] =
                (signed char)((hpack[mt] >> (8 * r)) & 255u);
        }
      }
      if (t + 1 < Tm && tid < 256) {   // stage x' for t+1
        int m = tid >> 2, c = tid & 3;
        int ch = CW[m][t + 1] & 255;
        *(i32x4*)&Xb[m >> 4][0][(m & 15) + 16 * c][0] = *(const i32x4*)&CT[ch][c * 16];
      }
      __syncthreads();
    } // t

    // ---- fused final linear: wave -> (mt0 = w>>2, col-group nw = w&3) ----
    int widA = order[base + mt0 * 16 + l15];
    f32x4 fac[4];
    #pragma unroll
    for (int nt = 0; nt < 4; ++nt) fac[nt] = 0.0f;

    #pragma unroll
    for (int kf = 0; kf < 16; ++kf) {              // K = 512
      short8 Bn[4];
      #pragma unroll
      for (int nt = 0; nt < 4; ++nt)
        Bn[nt] = ((const short8*)wlin)[((nw * 4 + nt) * 16 + kf) * 64 + lane];
      short8 Am;
      if (kf < 8) {                    // word_emb fp32 -> bf16
        const f32x4* pa = (const f32x4*)(wemb + widA * 256 + kf * 32 + q * 8);
        f32x4 f0 = pa[0], f1 = pa[1];
        Am[0] = (short)f2b(f0[0]); Am[1] = (short)f2b(f0[1]);
        Am[2] = (short)f2b(f0[2]); Am[3] = (short)f2b(f0[3]);
        Am[4] = (short)f2b(f1[0]); Am[5] = (short)f2b(f1[1]);
        Am[6] = (short)f2b(f1[2]); Am[7] = (short)f2b(f1[3]);
      } else {                         // final h from Xb i8 (K64 layout)
        int K0 = 64 + (kf - 8) * 32 + q * 8;
        long ch = *(const long*)&Xb[mt0][K0 >> 6][l15 + 16 * ((K0 >> 4) & 3)][K0 & 15];
        #pragma unroll
        for (int j = 0; j < 8; ++j) {
          int v = (int)(signed char)((ch >> (8 * j)) & 255);
          Am[j] = (short)f2b((float)v * (1.f / 127.f));
        }
      }
      #pragma unroll
      for (int nt = 0; nt < 4; ++nt) fac[nt] = MFMA16(Am, Bn[nt], fac[nt]);
    }
    #pragma unroll
    for (int r = 0; r < 4; ++r) {
      int wid = order[base + mt0 * 16 + q * 4 + r];
      float* po = outp + wid * 256 + nw * 64 + l15;
      #pragma unroll
      for (int nt = 0; nt < 4; ++nt) {
        float v = fac[nt][r] + blv[nt];
        po[nt * 16] = v > 0.f ? v : 0.f;
      }
    }
  } // slice
}

extern "C" void kernel_launch(void* const* d_in, const int* in_sizes, int n_in,
                              void* d_out, int out_size, void* d_ws, size_t ws_size,
                              hipStream_t stream) {
  const int*   cidx = (const int*)d_in[0];
  const int*   clen = (const int*)d_in[1];
  const float* wemb = (const float*)d_in[2];
  const float* ech  = (const float*)d_in[3];
  const float* wih  = (const float*)d_in[4];
  const float* whh  = (const float*)d_in[5];
  const float* bih  = (const float*)d_in[6];
  const float* bhh  = (const float*)d_in[7];
  const float* wlin = (const float*)d_in[8];
  const float* blin = (const float*)d_in[9];
  float* outp = (float*)d_out;
  unsigned char* ws = (unsigned char*)d_ws;

  k_prepA<<<336, 256, 0, stream>>>(wih, whh, bih, bhh, ech, clen, ws);
  k_prepB<<<1793, 256, 0, stream>>>(wih, whh, wlin, ws);
  k_scatter<<<128, 256, 0, stream>>>(clen, ws);
  k_main<<<256, 1024, 106496, stream>>>(cidx, wemb, blin, outp, ws);
}